// Round 1
// 343.730 us; speedup vs baseline: 1.0304x; 1.0304x over previous
//
#include <hip/hip_runtime.h>
#include <hip/hip_bf16.h>
#include <stdint.h>

// ---------------------------------------------------------------------------
// AstrocyteMemoryModule r8: 9 launches, no grid barriers.
//  L1 prep: converts + W^T + combined bias + accum bias-init + O/l zero
//  L2 Wc = Wi@W (batched 1024^3, BK=32, old 128^2 structure)
//  L3 NEW: gemm256 — 256^2-tile, BK=32, 4-deep LDS pipeline with counted
//     vmcnt(8) (T3+T4), setprio around MFMA (T5), proven chunk-XOR swizzle
//     (T2), XCD-banded mapping. 256 blocks = 1/CU, 512 thr, 128 KiB dyn LDS.
//     Computes kh (z=0) and vhT (z=1) + fused qh thin blocks (bid<16).
//  L4 flash (no-max exp; atomicAdd unnormalized O partials + row-sums l)
//  L5-L9 tail stages: split-K atomic GEMMs; S1 normalizes O by 1/l on-load;
//        later stages apply relu / sigmoid*ms on-load.
// ---------------------------------------------------------------------------

typedef __bf16 bf16;
typedef __bf16 bf16x4 __attribute__((ext_vector_type(4)));
typedef __bf16 bf16x8 __attribute__((ext_vector_type(8)));
typedef float f32x4 __attribute__((ext_vector_type(4)));

#define D_ 1024
#define M_ 8192
#define B_ 64
#define H_ 16

static __device__ __forceinline__ void gload16(const void* g, void* l) {
  __builtin_amdgcn_global_load_lds(
      (const __attribute__((address_space(1))) void*)g,
      (__attribute__((address_space(3))) void*)l, 16, 0, 0);
}

static __device__ __forceinline__ f32x4 mfma16(bf16x8 a, bf16x8 b, f32x4 c) {
  return __builtin_amdgcn_mfma_f32_16x16x32_bf16(a, b, c, 0, 0, 0);
}

// ---------------- thin GEMM (M=64): C = A @ B^T, reg-prefetched -------------
template <int U, int KLEN, typename OutT>
__device__ __forceinline__ void thin_gemm(
    const bf16* __restrict__ A, int lda,
    const bf16* __restrict__ Bm, int ldb,
    OutT* __restrict__ C, int ldc,
    const float* __restrict__ bias, float scale) {
  const int tid = threadIdx.x, lane = tid & 63, w = tid >> 6;
  const int rl = lane & 15, qq = lane >> 4;
  const bf16* pa = A + (int64_t)(w * 16 + rl) * lda + qq * 8;
  const bf16* pb[4];
  pb[0] = Bm + (int64_t)rl * ldb + qq * 8;
  pb[1] = pb[0] + (int64_t)16 * ldb;
  pb[2] = pb[0] + (int64_t)32 * ldb;
  pb[3] = pb[0] + (int64_t)48 * ldb;
  f32x4 acc[4] = {};
  bf16x8 av[2][U], bv[2][U][4];
#pragma unroll
  for (int u = 0; u < U; u++) {
    av[0][u] = *(const bf16x8*)(pa + u * 32);
#pragma unroll
    for (int j = 0; j < 4; j++)
      bv[0][u][j] = *(const bf16x8*)(pb[j] + u * 32);
  }
  constexpr int NI = KLEN / (32 * U);
#pragma unroll
  for (int it = 0; it < NI; it++) {
    const int cur = it & 1, nxt = cur ^ 1;
    if (it + 1 < NI) {
      int k = (it + 1) * 32 * U;
#pragma unroll
      for (int u = 0; u < U; u++) {
        av[nxt][u] = *(const bf16x8*)(pa + k + u * 32);
#pragma unroll
        for (int j = 0; j < 4; j++)
          bv[nxt][u][j] = *(const bf16x8*)(pb[j] + k + u * 32);
      }
    }
#pragma unroll
    for (int u = 0; u < U; u++)
#pragma unroll
      for (int j = 0; j < 4; j++)
        acc[j] = mfma16(av[cur][u], bv[cur][u][j], acc[j]);
  }
#pragma unroll
  for (int j = 0; j < 4; j++) {
    int gn = j * 16 + rl;
    float bb = bias ? bias[gn] : 0.0f;
#pragma unroll
    for (int r = 0; r < 4; r++) {
      int gm = w * 16 + qq * 4 + r;
      C[(int64_t)gm * ldc + gn] = (OutT)((acc[j][r] + bb) * scale);
    }
  }
}

// ------------------------------ prep (L1) ----------------------------------
// blocks: [0,29760) cvt, [29760,32832) W^T, [32832,33600) bias-combine,
//         [33600,33984) accum bias-init, [33984,34048) O/l zero
struct CvtD { const float* src; bf16* dst; int end; };
struct PrepArgs {
  CvtD d[9];
  const float *Wq, *Wk, *Wv, *inw, *inb, *bq, *bk, *bv;
  const float *outb, *gb1, *gb2, *ib1, *ib2;
  bf16* WT;
  float *bc, *msR, *g1R, *gateR, *h1R, *out, *Oraw, *lmat;
};

__global__ __launch_bounds__(256) void prep_kernel(PrepArgs a) {
  const int bx = blockIdx.x, tid = threadIdx.x;
  if (bx < 29760) {
    int g = bx * 256 + tid;
    CvtD dd = a.d[8];
    int begin = a.d[7].end;
#pragma unroll
    for (int t = 7; t >= 0; t--)
      if (g < a.d[t].end) { dd = a.d[t]; begin = t ? a.d[t - 1].end : 0; }
    int i = (g - begin) * 4;
    float4 v = *(const float4*)(dd.src + i);
    bf16x4 o = { (bf16)v.x, (bf16)v.y, (bf16)v.z, (bf16)v.w };
    *(bf16x4*)(dd.dst + i) = o;
  } else if (bx < 32832) {
    int t = bx - 29760;
    int z = t >> 10, rem = t & 1023;
    const float* src = z == 0 ? a.Wq : z == 1 ? a.Wk : a.Wv;
    bf16* out = a.WT + (int64_t)z * D_ * D_;
    __shared__ bf16 tile[32][33];
    int tx = tid & 31, ty = tid >> 5;
    int r0 = (rem >> 5) * 32, c0 = (rem & 31) * 32;
#pragma unroll
    for (int i = 0; i < 32; i += 8)
      tile[ty + i][tx] = (bf16)src[(int64_t)(r0 + ty + i) * D_ + c0 + tx];
    __syncthreads();
#pragma unroll
    for (int i = 0; i < 32; i += 8)
      out[(int64_t)(c0 + ty + i) * D_ + r0 + tx] = tile[tx][ty + i];
  } else if (bx < 33600) {
    int t = bx - 32832;
    int w = tid >> 6, lane = tid & 63;
    int ng = t * 4 + w;  // [0, 3072)
    int z = ng >> 10;
    const float* Wi = a.inw + (int64_t)ng * D_;
    const float* b = z == 0 ? a.bq : z == 1 ? a.bk : a.bv;
    float acc = 0.f;
#pragma unroll
    for (int l = 0; l < D_; l += 64) acc += Wi[l + lane] * b[l + lane];
#pragma unroll
    for (int m = 32; m; m >>= 1) acc += __shfl_xor(acc, m, 64);
    if (lane == 0) a.bc[ng] = acc + a.inb[ng];
  } else if (bx < 33984) {
    int t = bx - 33600;           // [0, 384)
    int seg = t >> 6, row = t & 63;
    int n = tid * 4;              // [0, 1024)
    const float* b;
    float* dst;
    int bn = n;
    if (seg == 0)      { dst = a.msR   + row * 1024;        b = a.outb; }
    else if (seg == 1) { dst = a.g1R   + row * 1024;        b = a.gb1;  }
    else if (seg == 2) { dst = a.gateR + row * 1024;        b = a.gb2;  }
    else if (seg == 3) { dst = a.h1R   + row * 2048;        b = a.ib1;  }
    else if (seg == 4) { dst = a.h1R   + row * 2048 + 1024; b = a.ib1; bn = 1024 + n; }
    else               { dst = a.out   + row * 1024;        b = a.ib2;  }
    *(float4*)(dst + n) = *(const float4*)(b + bn);
  } else {
    int b = bx - 33984;           // [0, 64): O/l zero
    float4 z4 = {0.f, 0.f, 0.f, 0.f};
    *(float4*)(a.Oraw + b * 1024 + tid * 4) = z4;
    if (b < 16 && tid < 64) a.lmat[b * 64 + tid] = 0.f;
  }
}

// ------------------------- big GEMM: C = A @ B^T (BK=32) -------------------
// (kept for L2 only: MODE 0)
template <int MODE>
__global__ __launch_bounds__(256) void gemm_big(
    const bf16* __restrict__ A, int lda, int64_t sA,
    const bf16* __restrict__ Bm, int ldb, int64_t sB,
    bf16* __restrict__ C, int ldc, int64_t sC, bf16* __restrict__ Ct,
    const float* __restrict__ bias, int64_t sbias, int K,
    const bf16* __restrict__ qA, const bf16* __restrict__ qB,
    bf16* __restrict__ qC, const float* __restrict__ qbias) {
  int m0, n0, z;
  if (MODE == 0) {
    z = blockIdx.z; m0 = blockIdx.y * 128; n0 = blockIdx.x * 128;
  } else {
    if ((int)blockIdx.x >= 1024) {  // fused qh: 16 thin blocks
      int n0q = ((int)blockIdx.x - 1024) * 64;
      thin_gemm<2, 1024, bf16>(qA, D_, qB + (int64_t)n0q * D_, D_,
                               qC + n0q, D_, qbias + n0q, 0.125f);
      return;
    }
    int lin = blockIdx.x, xcd = lin & 7, slot = lin >> 3;
    z = slot >> 6;
    int r = slot & 63;
    m0 = (xcd * 8 + (r >> 3)) * 128;  // XCD owns an M-band: A-tile reused 8x
    n0 = (r & 7) * 128;
  }
  A += (int64_t)z * sA; Bm += (int64_t)z * sB;
  if (bias) bias += (int64_t)z * sbias;
  __shared__ alignas(16) bf16 As[128 * 32];
  __shared__ alignas(16) bf16 Bs[128 * 32];
  const int tid = threadIdx.x, lane = tid & 63, w = tid >> 6;
  const int wm = (w & 1) * 64, wn = (w >> 1) * 64;
  const int rl = lane & 15, qq = lane >> 4;
  f32x4 acc[4][4] = {};

  int c0 = w * 64 + lane, c1 = (4 + w) * 64 + lane;
  int ra0 = c0 >> 2, qa0 = (c0 & 3) ^ ((ra0 >> 1) & 3);
  int ra1 = c1 >> 2, qa1 = (c1 & 3) ^ ((ra1 >> 1) & 3);
  const bf16* gA0 = A + (int64_t)(m0 + ra0) * lda + qa0 * 8;
  const bf16* gA1 = A + (int64_t)(m0 + ra1) * lda + qa1 * 8;
  const bf16* gB0 = Bm + (int64_t)(n0 + ra0) * ldb + qa0 * 8;
  const bf16* gB1 = Bm + (int64_t)(n0 + ra1) * ldb + qa1 * 8;
  bf16* lA0 = As + w * 512;
  bf16* lA1 = As + (4 + w) * 512;
  bf16* lB0 = Bs + w * 512;
  bf16* lB1 = Bs + (4 + w) * 512;

  for (int k0 = 0; k0 < K; k0 += 32) {
    __syncthreads();
    gload16(gA0 + k0, lA0);
    gload16(gA1 + k0, lA1);
    gload16(gB0 + k0, lB0);
    gload16(gB1 + k0, lB1);
    __syncthreads();
    bf16x8 af[4], bb[4];
#pragma unroll
    for (int i = 0; i < 4; i++) {
      int r = wm + i * 16 + rl;
      af[i] = *(const bf16x8*)(As + r * 32 + (qq ^ ((r >> 1) & 3)) * 8);
    }
#pragma unroll
    for (int j = 0; j < 4; j++) {
      int r = wn + j * 16 + rl;
      bb[j] = *(const bf16x8*)(Bs + r * 32 + (qq ^ ((r >> 1) & 3)) * 8);
    }
#pragma unroll
    for (int i = 0; i < 4; i++)
#pragma unroll
      for (int j = 0; j < 4; j++)
        acc[i][j] = mfma16(af[i], bb[j], acc[i][j]);
  }
  if (MODE == 1 && z == 1) {
#pragma unroll
    for (int j = 0; j < 4; j++) {
      int gn = n0 + wn + j * 16 + rl;
      float bb2 = bias ? bias[gn] : 0.0f;
#pragma unroll
      for (int i = 0; i < 4; i++) {
        int gm0 = m0 + wm + i * 16 + qq * 4;
        f32x4 a = acc[i][j];
        bf16x4 o = { (bf16)(a[0] + bb2), (bf16)(a[1] + bb2),
                     (bf16)(a[2] + bb2), (bf16)(a[3] + bb2) };
        *(bf16x4*)(Ct + (int64_t)gn * M_ + gm0) = o;
      }
    }
  } else {
    C += (int64_t)z * sC;
#pragma unroll
    for (int j = 0; j < 4; j++) {
      int gn = n0 + wn + j * 16 + rl;
      float bb2 = bias ? bias[gn] : 0.0f;
#pragma unroll
      for (int i = 0; i < 4; i++) {
        int gm0 = m0 + wm + i * 16 + qq * 4;
#pragma unroll
        for (int r = 0; r < 4; r++)
          C[(int64_t)(gm0 + r) * ldc + gn] = (bf16)(acc[i][j][r] + bb2);
      }
    }
  }
}

// ----------------- L3 NEW: 256^2-tile pipelined GEMM (kh + vhT) ------------
// grid: 16 thin qh blocks (bid<16) + 256 main blocks (1 per CU).
// Main block: 512 thr (8 waves, 2Mx4N), BK=32, 4 LDS buffers (128 KiB),
// prefetch depth 3: stage(kt+3); vmcnt(8); barrier; compute(kt); barrier.
// Same chunk-XOR swizzle as gemm_big (pre-swizzled global source).
__global__ __launch_bounds__(512) void gemm256(
    const bf16* __restrict__ A,    // mkmv (z=0: mk, z=1: mv)
    const bf16* __restrict__ Wc,   // Wc base; +D*D = Wc_k, +2D*D = Wc_v
    const float* __restrict__ bc,  // combined bias; +D = bik, +2D = biv
    bf16* __restrict__ kh, bf16* __restrict__ vhT,
    const bf16* __restrict__ qA, const bf16* __restrict__ qB,
    bf16* __restrict__ qC, const float* __restrict__ qbias) {
  extern __shared__ __align__(16) bf16 lds[];  // 4 * (8192 A + 8192 B) bf16
  const int bid = blockIdx.x;
  if (bid < 16) {
    if (threadIdx.x < 256) {
      int n0q = bid * 64;
      thin_gemm<2, 1024, bf16>(qA, D_, qB + (int64_t)n0q * D_, D_,
                               qC + n0q, D_, qbias + n0q, 0.125f);
    }
    return;
  }
  // XCD-banded mapping: bid%8 == lin%8 -> xcd; each XCD owns one z half and
  // an 8-tile M-band (A working set 4 MB = its L2).
  const int lin = bid - 16;
  const int xcd = lin & 7, s = lin >> 3;          // s in [0,32)
  const int z = xcd >> 2;                          // 0: kh, 1: vhT
  const int m0 = ((xcd & 3) * 8 + (s >> 2)) * 256; // [0, 8192)
  const int n0 = (s & 3) * 256;                    // [0, 1024)
  const bf16* Ab = A + (int64_t)z * M_ * D_;
  const bf16* Bb = Wc + (int64_t)(z + 1) * D_ * D_;
  const float* bias = bc + (z + 1) * D_;

  const int tid = threadIdx.x, lane = tid & 63, w = tid >> 6;
  const int rl = lane & 15, qq = lane >> 4;
  const int wr = w >> 2, wcn = w & 3;

  // staging: per wave 2 slots of 1 KiB per matrix; linear LDS dest,
  // pre-swizzled global source (chunk c_log = c_phys ^ ((row>>1)&3))
  const int ci0 = w * 128 + lane, ci1 = ci0 + 64;  // 16B-chunk idx [0,1024)
  const int ra0 = ci0 >> 2, ca0 = (ci0 & 3) ^ ((ra0 >> 1) & 3);
  const int ra1 = ci1 >> 2, ca1 = (ci1 & 3) ^ ((ra1 >> 1) & 3);
  const bf16* gA0 = Ab + (int64_t)(m0 + ra0) * D_ + ca0 * 8;
  const bf16* gA1 = Ab + (int64_t)(m0 + ra1) * D_ + ca1 * 8;
  const bf16* gB0 = Bb + (int64_t)(n0 + ra0) * D_ + ca0 * 8;
  const bf16* gB1 = Bb + (int64_t)(n0 + ra1) * D_ + ca1 * 8;
  const int lA0 = w * 1024, lA1 = lA0 + 512;  // element offsets in buffer

#define STAGE3(kt)                                   \
  do {                                               \
    bf16* bse = lds + ((kt) & 3) * 16384;            \
    int ko = (kt) * 32;                              \
    gload16(gA0 + ko, bse + lA0);                    \
    gload16(gA1 + ko, bse + lA1);                    \
    gload16(gB0 + ko, bse + 8192 + lA0);             \
    gload16(gB1 + ko, bse + 8192 + lA1);             \
  } while (0)
#define FENCE3 asm volatile("" ::: "memory")
#define BARRIER3                       \
  do {                                 \
    FENCE3;                            \
    __builtin_amdgcn_s_barrier();      \
    FENCE3;                            \
  } while (0)

  f32x4 acc[8][4] = {};
  const int sq8 = (qq ^ ((rl >> 1) & 3)) * 8;

  auto compute = [&](int kt) {
    const bf16* ba = lds + (kt & 3) * 16384;
    const bf16* bbp = ba + 8192;
    bf16x8 bfr[4], afr[4];
#pragma unroll
    for (int j = 0; j < 4; j++)
      bfr[j] = *(const bf16x8*)(bbp + (wcn * 64 + j * 16 + rl) * 32 + sq8);
#pragma unroll
    for (int mi = 0; mi < 4; mi++)
      afr[mi] = *(const bf16x8*)(ba + (wr * 128 + mi * 16 + rl) * 32 + sq8);
    __builtin_amdgcn_s_setprio(1);
#pragma unroll
    for (int mi = 0; mi < 4; mi++)
#pragma unroll
      for (int j = 0; j < 4; j++)
        acc[mi][j] = mfma16(afr[mi], bfr[j], acc[mi][j]);
    __builtin_amdgcn_s_setprio(0);
#pragma unroll
    for (int mi = 0; mi < 4; mi++)
      afr[mi] = *(const bf16x8*)(ba + (wr * 128 + (mi + 4) * 16 + rl) * 32 + sq8);
    __builtin_amdgcn_s_setprio(1);
#pragma unroll
    for (int mi = 0; mi < 4; mi++)
#pragma unroll
      for (int j = 0; j < 4; j++)
        acc[mi + 4][j] = mfma16(afr[mi], bfr[j], acc[mi + 4][j]);
    __builtin_amdgcn_s_setprio(0);
  };

  constexpr int NT = 32;  // K = 1024 / BK = 32
  STAGE3(0);
  STAGE3(1);
  STAGE3(2);
#pragma unroll 1
  for (int kt = 0; kt < NT - 2; kt++) {
    if (kt + 3 < NT) STAGE3(kt + 3);
    // counted wait: leave the 2 newest K-steps (8 loads) in flight
    asm volatile("s_waitcnt vmcnt(8)" ::: "memory");
    BARRIER3;
    compute(kt);
    BARRIER3;  // protect buf[(kt+4)&3] before next iter's stage
  }
  asm volatile("s_waitcnt vmcnt(4)" ::: "memory");
  BARRIER3;
  compute(NT - 2);
  asm volatile("s_waitcnt vmcnt(0)" ::: "memory");
  BARRIER3;
  compute(NT - 1);

  // epilogue
  if (z == 0) {
#pragma unroll
    for (int j = 0; j < 4; j++) {
      int gn = n0 + wcn * 64 + j * 16 + rl;
      float bb2 = bias[gn];
#pragma unroll
      for (int mi = 0; mi < 8; mi++) {
        int gm0 = m0 + wr * 128 + mi * 16 + qq * 4;
#pragma unroll
        for (int r = 0; r < 4; r++)
          kh[(int64_t)(gm0 + r) * D_ + gn] = (bf16)(acc[mi][j][r] + bb2);
      }
    }
  } else {
#pragma unroll
    for (int j = 0; j < 4; j++) {
      int gn = n0 + wcn * 64 + j * 16 + rl;
      float bb2 = bias[gn];
#pragma unroll
      for (int mi = 0; mi < 8; mi++) {
        int gm0 = m0 + wr * 128 + mi * 16 + qq * 4;
        f32x4 a = acc[mi][j];
        bf16x4 o = { (bf16)(a[0] + bb2), (bf16)(a[1] + bb2),
                     (bf16)(a[2] + bb2), (bf16)(a[3] + bb2) };
        *(bf16x4*)(vhT + (int64_t)gn * M_ + gm0) = o;
      }
    }
  }
#undef STAGE3
#undef FENCE3
#undef BARRIER3
}

// --------------------------- flash, no-max (L4) ----------------------------
// 256 blocks: h (16) x key-chunk c (16, 512 keys). Raw exp (scores tiny:
// sigma~0.17, |max|<1). Partials are plain sums -> atomicAdd into Oraw/lmat.
__global__ __launch_bounds__(256, 2) void flash_kernel(
    const bf16* __restrict__ qh, const bf16* __restrict__ kh,
    const bf16* __restrict__ vhT, float* __restrict__ Oraw,
    float* __restrict__ lmat) {
  const int tid = threadIdx.x, lane = tid & 63, w = tid >> 6;
  const int rl = lane & 15, qq = lane >> 4;
  const int h = blockIdx.x >> 4, c = blockIdx.x & 15;
  __shared__ alignas(16) bf16 Plds[4 * 16 * 72];
  const bf16* qhp = qh + (int64_t)(w * 16 + rl) * D_ + h * 64 + qq * 8;
  bf16x8 aq0 = *(const bf16x8*)(qhp);
  bf16x8 aq1 = *(const bf16x8*)(qhp + 32);
  float lsum[4] = {0.f, 0.f, 0.f, 0.f};
  f32x4 acc_o[4] = {};
  bf16* pl = Plds + w * 1152;
  const bf16* khb = kh + (int64_t)(c * 512) * D_ + h * 64 + qq * 8;
  const bf16* vtb = vhT + (int64_t)(h * 64) * M_ + c * 512 + qq * 8;
  for (int nt = 0; nt < 8; nt++) {
    int mb = nt * 64;
    bf16x8 bk0[4], bk1[4], vv0[4], vv1[4];
#pragma unroll
    for (int j = 0; j < 4; j++) {
      const bf16* p = khb + (int64_t)(mb + j * 16 + rl) * D_;
      bk0[j] = *(const bf16x8*)(p);
      bk1[j] = *(const bf16x8*)(p + 32);
      const bf16* q = vtb + (int64_t)(j * 16 + rl) * M_ + mb;
      vv0[j] = *(const bf16x8*)(q);
      vv1[j] = *(const bf16x8*)(q + 32);
    }
    f32x4 s[4] = {};
#pragma unroll
    for (int j = 0; j < 4; j++) {
      s[j] = mfma16(aq0, bk0[j], s[j]);
      s[j] = mfma16(aq1, bk1[j], s[j]);
    }
#pragma unroll
    for (int j = 0; j < 4; j++)
#pragma unroll
      for (int r = 0; r < 4; r++) {
        float p = __expf(s[j][r]);
        lsum[r] += p;
        pl[(qq * 4 + r) * 72 + j * 16 + rl] = (bf16)p;
      }
    bf16x8 pa0 = *(const bf16x8*)(pl + rl * 72 + qq * 8);
    bf16x8 pa1 = *(const bf16x8*)(pl + rl * 72 + 32 + qq * 8);
#pragma unroll
    for (int j = 0; j < 4; j++) {
      acc_o[j] = mfma16(pa0, vv0[j], acc_o[j]);
      acc_o[j] = mfma16(pa1, vv1[j], acc_o[j]);
    }
  }
#pragma unroll
  for (int msk = 1; msk <= 8; msk <<= 1)
#pragma unroll
    for (int r = 0; r < 4; r++) lsum[r] += __shfl_xor(lsum[r], msk, 64);
#pragma unroll
  for (int j = 0; j < 4; j++)
#pragma unroll
    for (int r = 0; r < 4; r++)
      atomicAdd(&Oraw[(int64_t)(w * 16 + qq * 4 + r) * D_ + h * 64 + j * 16 + rl],
                acc_o[j][r]);
  if (rl == 0)
#pragma unroll
    for (int r = 0; r < 4; r++)
      atomicAdd(&lmat[h * 64 + w * 16 + qq * 4 + r], lsum[r]);
}

// ----------------------- split-K atomic tail stage -------------------------
// Craw[m][n0..n0+64) += A_chunk(m, NKK*32) @ Bw_chunk^T, via atomicAdd.
// KIND: 0=bf16; 1=fp32; 2=relu(fp32); 3=sigmoid(p0)*p1; 4=p0*(1/l[h][m]).
struct Chunk { const void* p0; const void* p1; int ld; int kind; };
struct StageArgs { Chunk c[16]; };

template <int NKK>
__global__ __launch_bounds__(256) void tail_stage(
    StageArgs sa, const bf16* __restrict__ Bw, int ldb,
    float* __restrict__ Craw, int ldc) {
  const int n0 = blockIdx.x * 64, kc = blockIdx.y;
  const int bk0 = kc * NKK * 32;
  const Chunk ch = sa.c[kc];
  const int tid = threadIdx.x, lane = tid & 63, w = tid >> 6;
  const int rl = lane & 15, qq = lane >> 4;
  const int m = w * 16 + rl;
  const bf16* pb[4];
#pragma unroll
  for (int j = 0; j < 4; j++)
    pb[j] = Bw + (int64_t)(n0 + j * 16 + rl) * ldb + bk0 + qq * 8;
  f32x4 acc[4] = {};
#pragma unroll
  for (int kk = 0; kk < NKK; kk++) {
    bf16x8 af;
    if (ch.kind == 0) {
      af = *(const bf16x8*)((const bf16*)ch.p0 + (int64_t)m * ch.ld +
                            kk * 32 + qq * 8);
    } else {
      const float* p = (const float*)ch.p0 + (int64_t)m * ch.ld + kk * 32 + qq * 8;
      float4 u0 = *(const float4*)p;
      float4 u1 = *(const float4*)(p + 4);
      if (ch.kind == 2) {
        u0.x = fmaxf(u0.x, 0.f); u0.y = fmaxf(u0.y, 0.f);
        u0.z = fmaxf(u0.z, 0.f); u0.w = fmaxf(u0.w, 0.f);
        u1.x = fmaxf(u1.x, 0.f); u1.y = fmaxf(u1.y, 0.f);
        u1.z = fmaxf(u1.z, 0.f); u1.w = fmaxf(u1.w, 0.f);
      } else if (ch.kind == 3) {
        const float* pm = (const float*)ch.p1 + (int64_t)m * ch.ld + kk * 32 + qq * 8;
        float4 m0 = *(const float4*)pm;
        float4 m1 = *(const float4*)(pm + 4);
        u0.x = m0.x / (1.f + __expf(-u0.x)); u0.y = m0.y / (1.f + __expf(-u0.y));
        u0.z = m0.z / (1.f + __expf(-u0.z)); u0.w = m0.w / (1.f + __expf(-u0.w));
        u1.x = m1.x / (1.f + __expf(-u1.x)); u1.y = m1.y / (1.f + __expf(-u1.y));
        u1.z = m1.z / (1.f + __expf(-u1.z)); u1.w = m1.w / (1.f + __expf(-u1.w));
      } else if (ch.kind == 4) {
        int hidx = (bk0 + kk * 32) >> 6;
        float linv = 1.0f / ((const float*)ch.p1)[hidx * 64 + m];
        u0.x *= linv; u0.y *= linv; u0.z *= linv; u0.w *= linv;
        u1.x *= linv; u1.y *= linv; u1.z *= linv; u1.w *= linv;
      }
      af = (bf16x8){ (bf16)u0.x, (bf16)u0.y, (bf16)u0.z, (bf16)u0.w,
                     (bf16)u1.x, (bf16)u1.y, (bf16)u1.z, (bf16)u1.w };
    }
    bf16x8 bf_[4];
#pragma unroll
    for (int j = 0; j < 4; j++) bf_[j] = *(const bf16x8*)(pb[j] + kk * 32);
#pragma unroll
    for (int j = 0; j < 4; j++) acc[j] = mfma16(af, bf_[j], acc[j]);
  }
#pragma unroll
  for (int j = 0; j < 4; j++) {
    int gn = n0 + j * 16 + rl;
#pragma unroll
    for (int r = 0; r < 4; r++) {
      int gm = w * 16 + qq * 4 + r;
      atomicAdd(&Craw[(int64_t)gm * ldc + gn], acc[j][r]);
    }
  }
}

// ------------------------------- launch ------------------------------------
extern "C" void kernel_launch(void* const* d_in, const int* in_sizes, int n_in,
                              void* d_out, int out_size, void* d_ws,
                              size_t ws_size, hipStream_t stream) {
  (void)in_sizes; (void)n_in; (void)out_size;
  const float* x    = (const float*)d_in[0];
  const float* mk   = (const float*)d_in[1];
  const float* mv   = (const float*)d_in[2];
  const float* Wq   = (const float*)d_in[3];
  const float* bq   = (const float*)d_in[4];
  const float* Wk   = (const float*)d_in[5];
  const float* bk   = (const float*)d_in[6];
  const float* Wv   = (const float*)d_in[7];
  const float* bv   = (const float*)d_in[8];
  const float* inw  = (const float*)d_in[9];
  const float* inb  = (const float*)d_in[10];
  const float* outw = (const float*)d_in[11];
  const float* outb = (const float*)d_in[12];
  const float* gW1  = (const float*)d_in[13];
  const float* gb1  = (const float*)d_in[14];
  const float* gW2  = (const float*)d_in[15];
  const float* gb2  = (const float*)d_in[16];
  const float* iW1  = (const float*)d_in[17];
  const float* ib1  = (const float*)d_in[18];
  const float* iW2  = (const float*)d_in[19];
  const float* ib2  = (const float*)d_in[20];

  char* ws = (char*)d_ws;
  size_t off = 0;
  auto alloc = [&](size_t bytes) {
    char* p = ws + off;
    off += (bytes + 255) & ~(size_t)255;
    return p;
  };
  bf16* mkmv  = (bf16*)alloc((size_t)2 * M_ * D_ * 2);
  bf16* inpj  = (bf16*)alloc((size_t)3 * D_ * D_ * 2);
  bf16* WT    = (bf16*)alloc((size_t)3 * D_ * D_ * 2);
  bf16* Wc    = (bf16*)alloc((size_t)3 * D_ * D_ * 2);
  float* bc   = (float*)alloc(3 * D_ * 4);
  bf16* xbf   = (bf16*)alloc((size_t)B_ * D_ * 2);
  bf16* qh    = (bf16*)alloc((size_t)B_ * D_ * 2);
  bf16* kh    = (bf16*)alloc((size_t)M_ * D_ * 2);
  bf16* vhT   = (bf16*)alloc((size_t)M_ * D_ * 2);
  float* Oraw = (float*)alloc((size_t)B_ * D_ * 4);
  float* lmat = (float*)alloc((size_t)H_ * B_ * 4);
  float* msR  = (float*)alloc((size_t)B_ * D_ * 4);
  float* g1R  = (float*)alloc((size_t)B_ * D_ * 4);
  float* gateR= (float*)alloc((size_t)B_ * D_ * 4);
  float* h1R  = (float*)alloc((size_t)B_ * 2 * D_ * 4);
  bf16* gW1b  = (bf16*)alloc((size_t)D_ * 2 * D_ * 2);
  bf16* gW2b  = (bf16*)alloc((size_t)D_ * D_ * 2);
  bf16* iW1b  = (bf16*)alloc((size_t)2 * D_ * 2 * D_ * 2);
  bf16* iW2b  = (bf16*)alloc((size_t)D_ * 2 * D_ * 2);
  bf16* outwb = (bf16*)alloc((size_t)D_ * D_ * 2);
  if (ws_size < off) return;

  // L1: prep
  PrepArgs pa;
  pa.d[0] = { mk,   mkmv,           2097152 };
  pa.d[1] = { mv,   mkmv + M_ * D_, 4194304 };
  pa.d[2] = { inw,  inpj,           4980736 };
  pa.d[3] = { gW1,  gW1b,           5505024 };
  pa.d[4] = { gW2,  gW2b,           5767168 };
  pa.d[5] = { iW1,  iW1b,           6815744 };
  pa.d[6] = { iW2,  iW2b,           7340032 };
  pa.d[7] = { outw, outwb,          7602176 };
  pa.d[8] = { x,    xbf,            7618560 };
  pa.Wq = Wq; pa.Wk = Wk; pa.Wv = Wv; pa.inw = inw; pa.inb = inb;
  pa.bq = bq; pa.bk = bk; pa.bv = bv;
  pa.outb = outb; pa.gb1 = gb1; pa.gb2 = gb2; pa.ib1 = ib1; pa.ib2 = ib2;
  pa.WT = WT; pa.bc = bc; pa.msR = msR; pa.g1R = g1R; pa.gateR = gateR;
  pa.h1R = h1R; pa.out = (float*)d_out; pa.Oraw = Oraw; pa.lmat = lmat;
  prep_kernel<<<dim3(34048), 256, 0, stream>>>(pa);

  // L2: Wc_z = Wi_z @ W_z
  gemm_big<0><<<dim3(8, 8, 3), 256, 0, stream>>>(
      inpj, D_, (int64_t)D_ * D_, WT, D_, (int64_t)D_ * D_,
      Wc, D_, (int64_t)D_ * D_, nullptr, nullptr, 0, D_,
      nullptr, nullptr, nullptr, nullptr);

  // L3: kh / vhT via pipelined 256^2 kernel (+ fused qh thin blocks)
  hipFuncSetAttribute((const void*)gemm256,
                      hipFuncAttributeMaxDynamicSharedMemorySize, 131072);
  gemm256<<<dim3(272), dim3(512), 131072, stream>>>(
      mkmv, Wc, bc, kh, vhT, xbf, Wc, qh, bc);

  // L4: flash partials -> atomic Oraw / lmat
  flash_kernel<<<dim3(256), 256, 0, stream>>>(qh, kh, vhT, Oraw, lmat);

  // L5 S1: msR += (Oraw/l) @ outwb^T   grid (16 n, 8 kc of 128)
  StageArgs s1;
  for (int kc = 0; kc < 8; kc++) s1.c[kc] = { Oraw + kc * 128, lmat, D_, 4 };
  tail_stage<4><<<dim3(16, 8), 256, 0, stream>>>(s1, outwb, D_, msR, D_);

  // L6 S2: g1R += [x | msR] @ gW1^T    grid (16, 16 kc of 128, K=2048)
  StageArgs s2;
  for (int kc = 0; kc < 8; kc++)  s2.c[kc] = { xbf + kc * 128, nullptr, D_, 0 };
  for (int kc = 8; kc < 16; kc++) s2.c[kc] = { msR + (kc - 8) * 128, nullptr, D_, 1 };
  tail_stage<4><<<dim3(16, 16), 256, 0, stream>>>(s2, gW1b, 2 * D_, g1R, D_);

  // L7 S3: gateR += relu(g1R) @ gW2^T  grid (16, 8)
  StageArgs s3;
  for (int kc = 0; kc < 8; kc++) s3.c[kc] = { g1R + kc * 128, nullptr, D_, 2 };
  tail_stage<4><<<dim3(16, 8), 256, 0, stream>>>(s3, gW2b, D_, gateR, D_);

  // L8 S4: h1R += [x | sig(gateR)*msR] @ iW1^T  grid (32, 16)
  StageArgs s4;
  for (int kc = 0; kc < 8; kc++)  s4.c[kc] = { xbf + kc * 128, nullptr, D_, 0 };
  for (int kc = 8; kc < 16; kc++)
    s4.c[kc] = { gateR + (kc - 8) * 128, msR + (kc - 8) * 128, D_, 3 };
  tail_stage<4><<<dim3(32, 16), 256, 0, stream>>>(s4, iW1b, 2 * D_, h1R, 2 * D_);

  // L9 S5: out += relu(h1R) @ iW2^T    grid (16, 16, K=2048)
  StageArgs s5;
  for (int kc = 0; kc < 16; kc++) s5.c[kc] = { h1R + kc * 128, nullptr, 2 * D_, 2 };
  tail_stage<4><<<dim3(16, 16), 256, 0, stream>>>(s5, iW2b, 2 * D_,
                                                  (float*)d_out, D_);
}

// Round 2
// 338.952 us; speedup vs baseline: 1.0450x; 1.0141x over previous
//
#include <hip/hip_runtime.h>
#include <hip/hip_bf16.h>
#include <stdint.h>

// ---------------------------------------------------------------------------
// AstrocyteMemoryModule r9: 9 launches, no grid barriers.
//  L1 prep: converts + W^T + combined bias + accum bias-init + O/l zero
//  L2 Wc = Wi@W (batched 1024^3, BK=32, old 128^2 structure)
//  L3 gemm256 r2: 256^2-tile, BK=32, 4-buffer depth-3 pipeline.
//     Loop = { vmcnt(8) -> barrier -> STAGE(kt+3) -> compute(kt) }:
//     single barrier per K-step, wait covers 3 iterations (was 2), thin qh
//     blocks moved to grid TAIL (bid>=256) so stragglers are cheap.
//  L4 flash (no-max exp; atomicAdd unnormalized O partials + row-sums l)
//  L5-L9 tail stages: split-K atomic GEMMs; S1 normalizes O by 1/l on-load;
//        later stages apply relu / sigmoid*ms on-load.
// ---------------------------------------------------------------------------

typedef __bf16 bf16;
typedef __bf16 bf16x4 __attribute__((ext_vector_type(4)));
typedef __bf16 bf16x8 __attribute__((ext_vector_type(8)));
typedef float f32x4 __attribute__((ext_vector_type(4)));

#define D_ 1024
#define M_ 8192
#define B_ 64
#define H_ 16

static __device__ __forceinline__ void gload16(const void* g, void* l) {
  __builtin_amdgcn_global_load_lds(
      (const __attribute__((address_space(1))) void*)g,
      (__attribute__((address_space(3))) void*)l, 16, 0, 0);
}

static __device__ __forceinline__ f32x4 mfma16(bf16x8 a, bf16x8 b, f32x4 c) {
  return __builtin_amdgcn_mfma_f32_16x16x32_bf16(a, b, c, 0, 0, 0);
}

// ---------------- thin GEMM (M=64): C = A @ B^T, reg-prefetched -------------
template <int U, int KLEN, typename OutT>
__device__ __forceinline__ void thin_gemm(
    const bf16* __restrict__ A, int lda,
    const bf16* __restrict__ Bm, int ldb,
    OutT* __restrict__ C, int ldc,
    const float* __restrict__ bias, float scale) {
  const int tid = threadIdx.x, lane = tid & 63, w = tid >> 6;
  const int rl = lane & 15, qq = lane >> 4;
  const bf16* pa = A + (int64_t)(w * 16 + rl) * lda + qq * 8;
  const bf16* pb[4];
  pb[0] = Bm + (int64_t)rl * ldb + qq * 8;
  pb[1] = pb[0] + (int64_t)16 * ldb;
  pb[2] = pb[0] + (int64_t)32 * ldb;
  pb[3] = pb[0] + (int64_t)48 * ldb;
  f32x4 acc[4] = {};
  bf16x8 av[2][U], bv[2][U][4];
#pragma unroll
  for (int u = 0; u < U; u++) {
    av[0][u] = *(const bf16x8*)(pa + u * 32);
#pragma unroll
    for (int j = 0; j < 4; j++)
      bv[0][u][j] = *(const bf16x8*)(pb[j] + u * 32);
  }
  constexpr int NI = KLEN / (32 * U);
#pragma unroll
  for (int it = 0; it < NI; it++) {
    const int cur = it & 1, nxt = cur ^ 1;
    if (it + 1 < NI) {
      int k = (it + 1) * 32 * U;
#pragma unroll
      for (int u = 0; u < U; u++) {
        av[nxt][u] = *(const bf16x8*)(pa + k + u * 32);
#pragma unroll
        for (int j = 0; j < 4; j++)
          bv[nxt][u][j] = *(const bf16x8*)(pb[j] + k + u * 32);
      }
    }
#pragma unroll
    for (int u = 0; u < U; u++)
#pragma unroll
      for (int j = 0; j < 4; j++)
        acc[j] = mfma16(av[cur][u], bv[cur][u][j], acc[j]);
  }
#pragma unroll
  for (int j = 0; j < 4; j++) {
    int gn = j * 16 + rl;
    float bb = bias ? bias[gn] : 0.0f;
#pragma unroll
    for (int r = 0; r < 4; r++) {
      int gm = w * 16 + qq * 4 + r;
      C[(int64_t)gm * ldc + gn] = (OutT)((acc[j][r] + bb) * scale);
    }
  }
}

// ------------------------------ prep (L1) ----------------------------------
// blocks: [0,29760) cvt, [29760,32832) W^T, [32832,33600) bias-combine,
//         [33600,33984) accum bias-init, [33984,34048) O/l zero
struct CvtD { const float* src; bf16* dst; int end; };
struct PrepArgs {
  CvtD d[9];
  const float *Wq, *Wk, *Wv, *inw, *inb, *bq, *bk, *bv;
  const float *outb, *gb1, *gb2, *ib1, *ib2;
  bf16* WT;
  float *bc, *msR, *g1R, *gateR, *h1R, *out, *Oraw, *lmat;
};

__global__ __launch_bounds__(256) void prep_kernel(PrepArgs a) {
  const int bx = blockIdx.x, tid = threadIdx.x;
  if (bx < 29760) {
    int g = bx * 256 + tid;
    CvtD dd = a.d[8];
    int begin = a.d[7].end;
#pragma unroll
    for (int t = 7; t >= 0; t--)
      if (g < a.d[t].end) { dd = a.d[t]; begin = t ? a.d[t - 1].end : 0; }
    int i = (g - begin) * 4;
    float4 v = *(const float4*)(dd.src + i);
    bf16x4 o = { (bf16)v.x, (bf16)v.y, (bf16)v.z, (bf16)v.w };
    *(bf16x4*)(dd.dst + i) = o;
  } else if (bx < 32832) {
    int t = bx - 29760;
    int z = t >> 10, rem = t & 1023;
    const float* src = z == 0 ? a.Wq : z == 1 ? a.Wk : a.Wv;
    bf16* out = a.WT + (int64_t)z * D_ * D_;
    __shared__ bf16 tile[32][33];
    int tx = tid & 31, ty = tid >> 5;
    int r0 = (rem >> 5) * 32, c0 = (rem & 31) * 32;
#pragma unroll
    for (int i = 0; i < 32; i += 8)
      tile[ty + i][tx] = (bf16)src[(int64_t)(r0 + ty + i) * D_ + c0 + tx];
    __syncthreads();
#pragma unroll
    for (int i = 0; i < 32; i += 8)
      out[(int64_t)(c0 + ty + i) * D_ + r0 + tx] = tile[tx][ty + i];
  } else if (bx < 33600) {
    int t = bx - 32832;
    int w = tid >> 6, lane = tid & 63;
    int ng = t * 4 + w;  // [0, 3072)
    int z = ng >> 10;
    const float* Wi = a.inw + (int64_t)ng * D_;
    const float* b = z == 0 ? a.bq : z == 1 ? a.bk : a.bv;
    float acc = 0.f;
#pragma unroll
    for (int l = 0; l < D_; l += 64) acc += Wi[l + lane] * b[l + lane];
#pragma unroll
    for (int m = 32; m; m >>= 1) acc += __shfl_xor(acc, m, 64);
    if (lane == 0) a.bc[ng] = acc + a.inb[ng];
  } else if (bx < 33984) {
    int t = bx - 33600;           // [0, 384)
    int seg = t >> 6, row = t & 63;
    int n = tid * 4;              // [0, 1024)
    const float* b;
    float* dst;
    int bn = n;
    if (seg == 0)      { dst = a.msR   + row * 1024;        b = a.outb; }
    else if (seg == 1) { dst = a.g1R   + row * 1024;        b = a.gb1;  }
    else if (seg == 2) { dst = a.gateR + row * 1024;        b = a.gb2;  }
    else if (seg == 3) { dst = a.h1R   + row * 2048;        b = a.ib1;  }
    else if (seg == 4) { dst = a.h1R   + row * 2048 + 1024; b = a.ib1; bn = 1024 + n; }
    else               { dst = a.out   + row * 1024;        b = a.ib2;  }
    *(float4*)(dst + n) = *(const float4*)(b + bn);
  } else {
    int b = bx - 33984;           // [0, 64): O/l zero
    float4 z4 = {0.f, 0.f, 0.f, 0.f};
    *(float4*)(a.Oraw + b * 1024 + tid * 4) = z4;
    if (b < 16 && tid < 64) a.lmat[b * 64 + tid] = 0.f;
  }
}

// ------------------------- big GEMM: C = A @ B^T (BK=32) -------------------
// (kept for L2 only: MODE 0)
template <int MODE>
__global__ __launch_bounds__(256) void gemm_big(
    const bf16* __restrict__ A, int lda, int64_t sA,
    const bf16* __restrict__ Bm, int ldb, int64_t sB,
    bf16* __restrict__ C, int ldc, int64_t sC, bf16* __restrict__ Ct,
    const float* __restrict__ bias, int64_t sbias, int K,
    const bf16* __restrict__ qA, const bf16* __restrict__ qB,
    bf16* __restrict__ qC, const float* __restrict__ qbias) {
  int m0, n0, z;
  if (MODE == 0) {
    z = blockIdx.z; m0 = blockIdx.y * 128; n0 = blockIdx.x * 128;
  } else {
    if ((int)blockIdx.x >= 1024) {  // fused qh: 16 thin blocks
      int n0q = ((int)blockIdx.x - 1024) * 64;
      thin_gemm<2, 1024, bf16>(qA, D_, qB + (int64_t)n0q * D_, D_,
                               qC + n0q, D_, qbias + n0q, 0.125f);
      return;
    }
    int lin = blockIdx.x, xcd = lin & 7, slot = lin >> 3;
    z = slot >> 6;
    int r = slot & 63;
    m0 = (xcd * 8 + (r >> 3)) * 128;  // XCD owns an M-band: A-tile reused 8x
    n0 = (r & 7) * 128;
  }
  A += (int64_t)z * sA; Bm += (int64_t)z * sB;
  if (bias) bias += (int64_t)z * sbias;
  __shared__ alignas(16) bf16 As[128 * 32];
  __shared__ alignas(16) bf16 Bs[128 * 32];
  const int tid = threadIdx.x, lane = tid & 63, w = tid >> 6;
  const int wm = (w & 1) * 64, wn = (w >> 1) * 64;
  const int rl = lane & 15, qq = lane >> 4;
  f32x4 acc[4][4] = {};

  int c0 = w * 64 + lane, c1 = (4 + w) * 64 + lane;
  int ra0 = c0 >> 2, qa0 = (c0 & 3) ^ ((ra0 >> 1) & 3);
  int ra1 = c1 >> 2, qa1 = (c1 & 3) ^ ((ra1 >> 1) & 3);
  const bf16* gA0 = A + (int64_t)(m0 + ra0) * lda + qa0 * 8;
  const bf16* gA1 = A + (int64_t)(m0 + ra1) * lda + qa1 * 8;
  const bf16* gB0 = Bm + (int64_t)(n0 + ra0) * ldb + qa0 * 8;
  const bf16* gB1 = Bm + (int64_t)(n0 + ra1) * ldb + qa1 * 8;
  bf16* lA0 = As + w * 512;
  bf16* lA1 = As + (4 + w) * 512;
  bf16* lB0 = Bs + w * 512;
  bf16* lB1 = Bs + (4 + w) * 512;

  for (int k0 = 0; k0 < K; k0 += 32) {
    __syncthreads();
    gload16(gA0 + k0, lA0);
    gload16(gA1 + k0, lA1);
    gload16(gB0 + k0, lB0);
    gload16(gB1 + k0, lB1);
    __syncthreads();
    bf16x8 af[4], bb[4];
#pragma unroll
    for (int i = 0; i < 4; i++) {
      int r = wm + i * 16 + rl;
      af[i] = *(const bf16x8*)(As + r * 32 + (qq ^ ((r >> 1) & 3)) * 8);
    }
#pragma unroll
    for (int j = 0; j < 4; j++) {
      int r = wn + j * 16 + rl;
      bb[j] = *(const bf16x8*)(Bs + r * 32 + (qq ^ ((r >> 1) & 3)) * 8);
    }
#pragma unroll
    for (int i = 0; i < 4; i++)
#pragma unroll
      for (int j = 0; j < 4; j++)
        acc[i][j] = mfma16(af[i], bb[j], acc[i][j]);
  }
  if (MODE == 1 && z == 1) {
#pragma unroll
    for (int j = 0; j < 4; j++) {
      int gn = n0 + wn + j * 16 + rl;
      float bb2 = bias ? bias[gn] : 0.0f;
#pragma unroll
      for (int i = 0; i < 4; i++) {
        int gm0 = m0 + wm + i * 16 + qq * 4;
        f32x4 a = acc[i][j];
        bf16x4 o = { (bf16)(a[0] + bb2), (bf16)(a[1] + bb2),
                     (bf16)(a[2] + bb2), (bf16)(a[3] + bb2) };
        *(bf16x4*)(Ct + (int64_t)gn * M_ + gm0) = o;
      }
    }
  } else {
    C += (int64_t)z * sC;
#pragma unroll
    for (int j = 0; j < 4; j++) {
      int gn = n0 + wn + j * 16 + rl;
      float bb2 = bias ? bias[gn] : 0.0f;
#pragma unroll
      for (int i = 0; i < 4; i++) {
        int gm0 = m0 + wm + i * 16 + qq * 4;
#pragma unroll
        for (int r = 0; r < 4; r++)
          C[(int64_t)(gm0 + r) * ldc + gn] = (bf16)(acc[i][j][r] + bb2);
      }
    }
  }
}

// ----------------- L3: 256^2-tile pipelined GEMM (kh + vhT) ----------------
// grid: 256 main blocks (1 per CU) + 16 thin qh blocks at the TAIL.
// Main block: 512 thr (8 waves, 2Mx4N), BK=32, 4 LDS buffers (128 KiB).
// Loop: { vmcnt(8) -> barrier -> STAGE(kt+3) -> compute(kt) }.
//  - vmcnt(8) BEFORE the new stage waits only for stage kt (issued 3 iters
//    ago): max outstanding at that point = stages {kt,kt+1,kt+2} = 12 loads;
//    <=8 left  =>  oldest (kt) fully retired. Depth-3 latency cover.
//  - the single barrier both publishes stage kt (each wave passed its own
//    vmcnt) and proves compute(kt-1) done before STAGE(kt+3) overwrites
//    buf[(kt-1)&3].
__global__ __launch_bounds__(512) void gemm256(
    const bf16* __restrict__ A,    // mkmv (z=0: mk, z=1: mv)
    const bf16* __restrict__ Wc,   // Wc base; +D*D = Wc_k, +2D*D = Wc_v
    const float* __restrict__ bc,  // combined bias; +D = bik, +2D = biv
    bf16* __restrict__ kh, bf16* __restrict__ vhT,
    const bf16* __restrict__ qA, const bf16* __restrict__ qB,
    bf16* __restrict__ qC, const float* __restrict__ qbias) {
  extern __shared__ __align__(16) bf16 lds[];  // 4 * (8192 A + 8192 B) bf16
  const int bid = blockIdx.x;
  if (bid >= 256) {  // thin qh blocks at grid tail: start on first-freed CUs
    if (threadIdx.x < 256) {
      int n0q = (bid - 256) * 64;
      thin_gemm<2, 1024, bf16>(qA, D_, qB + (int64_t)n0q * D_, D_,
                               qC + n0q, D_, qbias + n0q, 0.125f);
    }
    return;
  }
  // XCD-banded mapping: bid%8 -> xcd; each XCD owns one z half and an
  // 8-tile M-band (A working set 4 MB = its L2).
  const int lin = bid;
  const int xcd = lin & 7, s = lin >> 3;          // s in [0,32)
  const int z = xcd >> 2;                          // 0: kh, 1: vhT
  const int m0 = ((xcd & 3) * 8 + (s >> 2)) * 256; // [0, 8192)
  const int n0 = (s & 3) * 256;                    // [0, 1024)
  const bf16* Ab = A + (int64_t)z * M_ * D_;
  const bf16* Bb = Wc + (int64_t)(z + 1) * D_ * D_;
  const float* bias = bc + (z + 1) * D_;

  const int tid = threadIdx.x, lane = tid & 63, w = tid >> 6;
  const int rl = lane & 15, qq = lane >> 4;
  const int wr = w >> 2, wcn = w & 3;

  // staging: per wave 2 slots of 1 KiB per matrix; linear LDS dest,
  // pre-swizzled global source (chunk c_log = c_phys ^ ((row>>1)&3))
  const int ci0 = w * 128 + lane, ci1 = ci0 + 64;  // 16B-chunk idx [0,1024)
  const int ra0 = ci0 >> 2, ca0 = (ci0 & 3) ^ ((ra0 >> 1) & 3);
  const int ra1 = ci1 >> 2, ca1 = (ci1 & 3) ^ ((ra1 >> 1) & 3);
  const bf16* gA0 = Ab + (int64_t)(m0 + ra0) * D_ + ca0 * 8;
  const bf16* gA1 = Ab + (int64_t)(m0 + ra1) * D_ + ca1 * 8;
  const bf16* gB0 = Bb + (int64_t)(n0 + ra0) * D_ + ca0 * 8;
  const bf16* gB1 = Bb + (int64_t)(n0 + ra1) * D_ + ca1 * 8;
  const int lA0 = w * 1024, lA1 = lA0 + 512;  // element offsets in buffer

#define STAGE3(kt)                                   \
  do {                                               \
    bf16* bse = lds + ((kt) & 3) * 16384;            \
    int ko = (kt) * 32;                              \
    gload16(gA0 + ko, bse + lA0);                    \
    gload16(gA1 + ko, bse + lA1);                    \
    gload16(gB0 + ko, bse + 8192 + lA0);             \
    gload16(gB1 + ko, bse + 8192 + lA1);             \
  } while (0)
#define FENCE3 asm volatile("" ::: "memory")
#define BARRIER3                       \
  do {                                 \
    FENCE3;                            \
    __builtin_amdgcn_s_barrier();      \
    FENCE3;                            \
  } while (0)

  f32x4 acc[8][4] = {};
  const int sq8 = (qq ^ ((rl >> 1) & 3)) * 8;

  auto compute = [&](int kt) {
    const bf16* ba = lds + (kt & 3) * 16384;
    const bf16* bbp = ba + 8192;
    bf16x8 bfr[4], afr[8];
#pragma unroll
    for (int j = 0; j < 4; j++)
      bfr[j] = *(const bf16x8*)(bbp + (wcn * 64 + j * 16 + rl) * 32 + sq8);
#pragma unroll
    for (int mi = 0; mi < 8; mi++)
      afr[mi] = *(const bf16x8*)(ba + (wr * 128 + mi * 16 + rl) * 32 + sq8);
    __builtin_amdgcn_s_setprio(1);
#pragma unroll
    for (int mi = 0; mi < 8; mi++)
#pragma unroll
      for (int j = 0; j < 4; j++)
        acc[mi][j] = mfma16(afr[mi], bfr[j], acc[mi][j]);
    __builtin_amdgcn_s_setprio(0);
  };

  constexpr int NT = 32;  // K = 1024 / BK = 32
  STAGE3(0);
  STAGE3(1);
  STAGE3(2);
#pragma unroll 1
  for (int kt = 0; kt < NT - 2; kt++) {
    asm volatile("s_waitcnt vmcnt(8)" ::: "memory");
    BARRIER3;
    if (kt + 3 < NT) STAGE3(kt + 3);
    compute(kt);
  }
  asm volatile("s_waitcnt vmcnt(4)" ::: "memory");
  BARRIER3;
  compute(NT - 2);
  asm volatile("s_waitcnt vmcnt(0)" ::: "memory");
  BARRIER3;
  compute(NT - 1);

  // epilogue
  if (z == 0) {
#pragma unroll
    for (int j = 0; j < 4; j++) {
      int gn = n0 + wcn * 64 + j * 16 + rl;
      float bb2 = bias[gn];
#pragma unroll
      for (int mi = 0; mi < 8; mi++) {
        int gm0 = m0 + wr * 128 + mi * 16 + qq * 4;
#pragma unroll
        for (int r = 0; r < 4; r++)
          kh[(int64_t)(gm0 + r) * D_ + gn] = (bf16)(acc[mi][j][r] + bb2);
      }
    }
  } else {
#pragma unroll
    for (int j = 0; j < 4; j++) {
      int gn = n0 + wcn * 64 + j * 16 + rl;
      float bb2 = bias[gn];
#pragma unroll
      for (int mi = 0; mi < 8; mi++) {
        int gm0 = m0 + wr * 128 + mi * 16 + qq * 4;
        f32x4 a = acc[mi][j];
        bf16x4 o = { (bf16)(a[0] + bb2), (bf16)(a[1] + bb2),
                     (bf16)(a[2] + bb2), (bf16)(a[3] + bb2) };
        *(bf16x4*)(vhT + (int64_t)gn * M_ + gm0) = o;
      }
    }
  }
#undef STAGE3
#undef FENCE3
#undef BARRIER3
}

// --------------------------- flash, no-max (L4) ----------------------------
// 256 blocks: h (16) x key-chunk c (16, 512 keys). Raw exp (scores tiny:
// sigma~0.17, |max|<1). Partials are plain sums -> atomicAdd into Oraw/lmat.
__global__ __launch_bounds__(256, 2) void flash_kernel(
    const bf16* __restrict__ qh, const bf16* __restrict__ kh,
    const bf16* __restrict__ vhT, float* __restrict__ Oraw,
    float* __restrict__ lmat) {
  const int tid = threadIdx.x, lane = tid & 63, w = tid >> 6;
  const int rl = lane & 15, qq = lane >> 4;
  const int h = blockIdx.x >> 4, c = blockIdx.x & 15;
  __shared__ alignas(16) bf16 Plds[4 * 16 * 72];
  const bf16* qhp = qh + (int64_t)(w * 16 + rl) * D_ + h * 64 + qq * 8;
  bf16x8 aq0 = *(const bf16x8*)(qhp);
  bf16x8 aq1 = *(const bf16x8*)(qhp + 32);
  float lsum[4] = {0.f, 0.f, 0.f, 0.f};
  f32x4 acc_o[4] = {};
  bf16* pl = Plds + w * 1152;
  const bf16* khb = kh + (int64_t)(c * 512) * D_ + h * 64 + qq * 8;
  const bf16* vtb = vhT + (int64_t)(h * 64) * M_ + c * 512 + qq * 8;
  for (int nt = 0; nt < 8; nt++) {
    int mb = nt * 64;
    bf16x8 bk0[4], bk1[4], vv0[4], vv1[4];
#pragma unroll
    for (int j = 0; j < 4; j++) {
      const bf16* p = khb + (int64_t)(mb + j * 16 + rl) * D_;
      bk0[j] = *(const bf16x8*)(p);
      bk1[j] = *(const bf16x8*)(p + 32);
      const bf16* q = vtb + (int64_t)(j * 16 + rl) * M_ + mb;
      vv0[j] = *(const bf16x8*)(q);
      vv1[j] = *(const bf16x8*)(q + 32);
    }
    f32x4 s[4] = {};
#pragma unroll
    for (int j = 0; j < 4; j++) {
      s[j] = mfma16(aq0, bk0[j], s[j]);
      s[j] = mfma16(aq1, bk1[j], s[j]);
    }
#pragma unroll
    for (int j = 0; j < 4; j++)
#pragma unroll
      for (int r = 0; r < 4; r++) {
        float p = __expf(s[j][r]);
        lsum[r] += p;
        pl[(qq * 4 + r) * 72 + j * 16 + rl] = (bf16)p;
      }
    bf16x8 pa0 = *(const bf16x8*)(pl + rl * 72 + qq * 8);
    bf16x8 pa1 = *(const bf16x8*)(pl + rl * 72 + 32 + qq * 8);
#pragma unroll
    for (int j = 0; j < 4; j++) {
      acc_o[j] = mfma16(pa0, vv0[j], acc_o[j]);
      acc_o[j] = mfma16(pa1, vv1[j], acc_o[j]);
    }
  }
#pragma unroll
  for (int msk = 1; msk <= 8; msk <<= 1)
#pragma unroll
    for (int r = 0; r < 4; r++) lsum[r] += __shfl_xor(lsum[r], msk, 64);
#pragma unroll
  for (int j = 0; j < 4; j++)
#pragma unroll
    for (int r = 0; r < 4; r++)
      atomicAdd(&Oraw[(int64_t)(w * 16 + qq * 4 + r) * D_ + h * 64 + j * 16 + rl],
                acc_o[j][r]);
  if (rl == 0)
#pragma unroll
    for (int r = 0; r < 4; r++)
      atomicAdd(&lmat[h * 64 + w * 16 + qq * 4 + r], lsum[r]);
}

// ----------------------- split-K atomic tail stage -------------------------
// Craw[m][n0..n0+64) += A_chunk(m, NKK*32) @ Bw_chunk^T, via atomicAdd.
// KIND: 0=bf16; 1=fp32; 2=relu(fp32); 3=sigmoid(p0)*p1; 4=p0*(1/l[h][m]).
struct Chunk { const void* p0; const void* p1; int ld; int kind; };
struct StageArgs { Chunk c[16]; };

template <int NKK>
__global__ __launch_bounds__(256) void tail_stage(
    StageArgs sa, const bf16* __restrict__ Bw, int ldb,
    float* __restrict__ Craw, int ldc) {
  const int n0 = blockIdx.x * 64, kc = blockIdx.y;
  const int bk0 = kc * NKK * 32;
  const Chunk ch = sa.c[kc];
  const int tid = threadIdx.x, lane = tid & 63, w = tid >> 6;
  const int rl = lane & 15, qq = lane >> 4;
  const int m = w * 16 + rl;
  const bf16* pb[4];
#pragma unroll
  for (int j = 0; j < 4; j++)
    pb[j] = Bw + (int64_t)(n0 + j * 16 + rl) * ldb + bk0 + qq * 8;
  f32x4 acc[4] = {};
#pragma unroll
  for (int kk = 0; kk < NKK; kk++) {
    bf16x8 af;
    if (ch.kind == 0) {
      af = *(const bf16x8*)((const bf16*)ch.p0 + (int64_t)m * ch.ld +
                            kk * 32 + qq * 8);
    } else {
      const float* p = (const float*)ch.p0 + (int64_t)m * ch.ld + kk * 32 + qq * 8;
      float4 u0 = *(const float4*)p;
      float4 u1 = *(const float4*)(p + 4);
      if (ch.kind == 2) {
        u0.x = fmaxf(u0.x, 0.f); u0.y = fmaxf(u0.y, 0.f);
        u0.z = fmaxf(u0.z, 0.f); u0.w = fmaxf(u0.w, 0.f);
        u1.x = fmaxf(u1.x, 0.f); u1.y = fmaxf(u1.y, 0.f);
        u1.z = fmaxf(u1.z, 0.f); u1.w = fmaxf(u1.w, 0.f);
      } else if (ch.kind == 3) {
        const float* pm = (const float*)ch.p1 + (int64_t)m * ch.ld + kk * 32 + qq * 8;
        float4 m0 = *(const float4*)pm;
        float4 m1 = *(const float4*)(pm + 4);
        u0.x = m0.x / (1.f + __expf(-u0.x)); u0.y = m0.y / (1.f + __expf(-u0.y));
        u0.z = m0.z / (1.f + __expf(-u0.z)); u0.w = m0.w / (1.f + __expf(-u0.w));
        u1.x = m1.x / (1.f + __expf(-u1.x)); u1.y = m1.y / (1.f + __expf(-u1.y));
        u1.z = m1.z / (1.f + __expf(-u1.z)); u1.w = m1.w / (1.f + __expf(-u1.w));
      } else if (ch.kind == 4) {
        int hidx = (bk0 + kk * 32) >> 6;
        float linv = 1.0f / ((const float*)ch.p1)[hidx * 64 + m];
        u0.x *= linv; u0.y *= linv; u0.z *= linv; u0.w *= linv;
        u1.x *= linv; u1.y *= linv; u1.z *= linv; u1.w *= linv;
      }
      af = (bf16x8){ (bf16)u0.x, (bf16)u0.y, (bf16)u0.z, (bf16)u0.w,
                     (bf16)u1.x, (bf16)u1.y, (bf16)u1.z, (bf16)u1.w };
    }
    bf16x8 bf_[4];
#pragma unroll
    for (int j = 0; j < 4; j++) bf_[j] = *(const bf16x8*)(pb[j] + kk * 32);
#pragma unroll
    for (int j = 0; j < 4; j++) acc[j] = mfma16(af, bf_[j], acc[j]);
  }
#pragma unroll
  for (int j = 0; j < 4; j++) {
    int gn = n0 + j * 16 + rl;
#pragma unroll
    for (int r = 0; r < 4; r++) {
      int gm = w * 16 + qq * 4 + r;
      atomicAdd(&Craw[(int64_t)gm * ldc + gn], acc[j][r]);
    }
  }
}

// ------------------------------- launch ------------------------------------
extern "C" void kernel_launch(void* const* d_in, const int* in_sizes, int n_in,
                              void* d_out, int out_size, void* d_ws,
                              size_t ws_size, hipStream_t stream) {
  (void)in_sizes; (void)n_in; (void)out_size;
  const float* x    = (const float*)d_in[0];
  const float* mk   = (const float*)d_in[1];
  const float* mv   = (const float*)d_in[2];
  const float* Wq   = (const float*)d_in[3];
  const float* bq   = (const float*)d_in[4];
  const float* Wk   = (const float*)d_in[5];
  const float* bk   = (const float*)d_in[6];
  const float* Wv   = (const float*)d_in[7];
  const float* bv   = (const float*)d_in[8];
  const float* inw  = (const float*)d_in[9];
  const float* inb  = (const float*)d_in[10];
  const float* outw = (const float*)d_in[11];
  const float* outb = (const float*)d_in[12];
  const float* gW1  = (const float*)d_in[13];
  const float* gb1  = (const float*)d_in[14];
  const float* gW2  = (const float*)d_in[15];
  const float* gb2  = (const float*)d_in[16];
  const float* iW1  = (const float*)d_in[17];
  const float* ib1  = (const float*)d_in[18];
  const float* iW2  = (const float*)d_in[19];
  const float* ib2  = (const float*)d_in[20];

  char* ws = (char*)d_ws;
  size_t off = 0;
  auto alloc = [&](size_t bytes) {
    char* p = ws + off;
    off += (bytes + 255) & ~(size_t)255;
    return p;
  };
  bf16* mkmv  = (bf16*)alloc((size_t)2 * M_ * D_ * 2);
  bf16* inpj  = (bf16*)alloc((size_t)3 * D_ * D_ * 2);
  bf16* WT    = (bf16*)alloc((size_t)3 * D_ * D_ * 2);
  bf16* Wc    = (bf16*)alloc((size_t)3 * D_ * D_ * 2);
  float* bc   = (float*)alloc(3 * D_ * 4);
  bf16* xbf   = (bf16*)alloc((size_t)B_ * D_ * 2);
  bf16* qh    = (bf16*)alloc((size_t)B_ * D_ * 2);
  bf16* kh    = (bf16*)alloc((size_t)M_ * D_ * 2);
  bf16* vhT   = (bf16*)alloc((size_t)M_ * D_ * 2);
  float* Oraw = (float*)alloc((size_t)B_ * D_ * 4);
  float* lmat = (float*)alloc((size_t)H_ * B_ * 4);
  float* msR  = (float*)alloc((size_t)B_ * D_ * 4);
  float* g1R  = (float*)alloc((size_t)B_ * D_ * 4);
  float* gateR= (float*)alloc((size_t)B_ * D_ * 4);
  float* h1R  = (float*)alloc((size_t)B_ * 2 * D_ * 4);
  bf16* gW1b  = (bf16*)alloc((size_t)D_ * 2 * D_ * 2);
  bf16* gW2b  = (bf16*)alloc((size_t)D_ * D_ * 2);
  bf16* iW1b  = (bf16*)alloc((size_t)2 * D_ * 2 * D_ * 2);
  bf16* iW2b  = (bf16*)alloc((size_t)D_ * 2 * D_ * 2);
  bf16* outwb = (bf16*)alloc((size_t)D_ * D_ * 2);
  if (ws_size < off) return;

  // L1: prep
  PrepArgs pa;
  pa.d[0] = { mk,   mkmv,           2097152 };
  pa.d[1] = { mv,   mkmv + M_ * D_, 4194304 };
  pa.d[2] = { inw,  inpj,           4980736 };
  pa.d[3] = { gW1,  gW1b,           5505024 };
  pa.d[4] = { gW2,  gW2b,           5767168 };
  pa.d[5] = { iW1,  iW1b,           6815744 };
  pa.d[6] = { iW2,  iW2b,           7340032 };
  pa.d[7] = { outw, outwb,          7602176 };
  pa.d[8] = { x,    xbf,            7618560 };
  pa.Wq = Wq; pa.Wk = Wk; pa.Wv = Wv; pa.inw = inw; pa.inb = inb;
  pa.bq = bq; pa.bk = bk; pa.bv = bv;
  pa.outb = outb; pa.gb1 = gb1; pa.gb2 = gb2; pa.ib1 = ib1; pa.ib2 = ib2;
  pa.WT = WT; pa.bc = bc; pa.msR = msR; pa.g1R = g1R; pa.gateR = gateR;
  pa.h1R = h1R; pa.out = (float*)d_out; pa.Oraw = Oraw; pa.lmat = lmat;
  prep_kernel<<<dim3(34048), 256, 0, stream>>>(pa);

  // L2: Wc_z = Wi_z @ W_z
  gemm_big<0><<<dim3(8, 8, 3), 256, 0, stream>>>(
      inpj, D_, (int64_t)D_ * D_, WT, D_, (int64_t)D_ * D_,
      Wc, D_, (int64_t)D_ * D_, nullptr, nullptr, 0, D_,
      nullptr, nullptr, nullptr, nullptr);

  // L3: kh / vhT via pipelined 256^2 kernel (+ qh thin blocks at grid tail)
  hipFuncSetAttribute((const void*)gemm256,
                      hipFuncAttributeMaxDynamicSharedMemorySize, 131072);
  gemm256<<<dim3(272), dim3(512), 131072, stream>>>(
      mkmv, Wc, bc, kh, vhT, xbf, Wc, qh, bc);

  // L4: flash partials -> atomic Oraw / lmat
  flash_kernel<<<dim3(256), 256, 0, stream>>>(qh, kh, vhT, Oraw, lmat);

  // L5 S1: msR += (Oraw/l) @ outwb^T   grid (16 n, 8 kc of 128)
  StageArgs s1;
  for (int kc = 0; kc < 8; kc++) s1.c[kc] = { Oraw + kc * 128, lmat, D_, 4 };
  tail_stage<4><<<dim3(16, 8), 256, 0, stream>>>(s1, outwb, D_, msR, D_);

  // L6 S2: g1R += [x | msR] @ gW1^T    grid (16, 16 kc of 128, K=2048)
  StageArgs s2;
  for (int kc = 0; kc < 8; kc++)  s2.c[kc] = { xbf + kc * 128, nullptr, D_, 0 };
  for (int kc = 8; kc < 16; kc++) s2.c[kc] = { msR + (kc - 8) * 128, nullptr, D_, 1 };
  tail_stage<4><<<dim3(16, 16), 256, 0, stream>>>(s2, gW1b, 2 * D_, g1R, D_);

  // L7 S3: gateR += relu(g1R) @ gW2^T  grid (16, 8)
  StageArgs s3;
  for (int kc = 0; kc < 8; kc++) s3.c[kc] = { g1R + kc * 128, nullptr, D_, 2 };
  tail_stage<4><<<dim3(16, 8), 256, 0, stream>>>(s3, gW2b, D_, gateR, D_);

  // L8 S4: h1R += [x | sig(gateR)*msR] @ iW1^T  grid (32, 16)
  StageArgs s4;
  for (int kc = 0; kc < 8; kc++)  s4.c[kc] = { xbf + kc * 128, nullptr, D_, 0 };
  for (int kc = 8; kc < 16; kc++)
    s4.c[kc] = { gateR + (kc - 8) * 128, msR + (kc - 8) * 128, D_, 3 };
  tail_stage<4><<<dim3(32, 16), 256, 0, stream>>>(s4, iW1b, 2 * D_, h1R, 2 * D_);

  // L9 S5: out += relu(h1R) @ iW2^T    grid (16, 16, K=2048)
  StageArgs s5;
  for (int kc = 0; kc < 16; kc++) s5.c[kc] = { h1R + kc * 128, nullptr, 2 * D_, 2 };
  tail_stage<4><<<dim3(16, 16), 256, 0, stream>>>(s5, iW2b, 2 * D_,
                                                  (float*)d_out, D_);
}